// Round 1
// baseline (16859.367 us; speedup 1.0000x reference)
//
#include <hip/hip_runtime.h>

// ---------------- problem constants ----------------
#define TT   2048          // timesteps
#define NB   16            // batch
#define HH   512           // hidden
#define NSL  32            // workgroups per layer (hidden slices)
#define HSL  16            // hidden units per slice
#define KW   128           // K-range per wave (4 waves * 128 = 512)
#define Y_SZ (NB*TT*32)    // y output elements

typedef __attribute__((ext_vector_type(8))) short bf16x8;
typedef __attribute__((ext_vector_type(4))) float f32x4;

// ---------------- workspace layout (bytes) ----------------
// F1/F2: per-(step, wg) completion flags, 32 uints per step, steps 0..2048
// H*:    h state slots, slot s = h before step s (slot 0 = zeros), bf16 hi/lo
#define WS_F1 0u
#define WS_F2 327680u
#define WS_H  655360u
#define HARR  ((size_t)(TT+1)*NB*HH)   // ushorts per h array

__device__ __forceinline__ unsigned short f2bf(float x){
  unsigned u = __float_as_uint(x);
  return (unsigned short)((u + 0x7FFFu + ((u >> 16) & 1u)) >> 16);
}
__device__ __forceinline__ float bf2f(unsigned short b){
  return __uint_as_float(((unsigned)b) << 16);
}
__device__ __forceinline__ float sigm(float v){ return 1.0f / (1.0f + __expf(-v)); }
__device__ __forceinline__ float tanh_f(float v){
  float a = fabsf(v);
  float e = __expf(-2.0f * a);
  float t = (1.0f - e) / (1.0f + e);
  return v < 0.0f ? -t : t;
}
// split fp32 -> bf16 hi + bf16 lo (hi+lo reproduces fp32 to ~2^-17 rel)
__device__ __forceinline__ void split8(const float* __restrict__ p, bf16x8& hi, bf16x8& lo){
#pragma unroll
  for (int j = 0; j < 8; ++j){
    float w = p[j];
    unsigned short h = f2bf(w);
    hi[j] = (short)h;
    lo[j] = (short)f2bf(w - bf2f(h));
  }
}
// scan one step's 32 per-WG flags (128B); caller fences before calling
__device__ __forceinline__ bool flags_done(const unsigned* __restrict__ p){
  unsigned s = 0;
#pragma unroll
  for (int i = 0; i < 8; ++i){
    uint4 v = ((const uint4*)p)[i];
    s += v.x + v.y + v.z + v.w;
  }
  return s == NSL;
}

// =====================================================================
// Persistent 2-layer LSTM. 64 WGs: wg 0..31 = layer0, 32..63 = layer1.
// Each WG owns 16 hidden units (64 gate rows). Weights pinned in VGPRs as
// bf16 hi/lo fragments; 3-pass split MFMA gives ~fp32 accuracy.
// Wave w handles K-slice [w*128, w*128+128); partials reduced via LDS.
// =====================================================================
__global__ __launch_bounds__(256, 1) void lstm_persist(
    const float* __restrict__ x,
    const float* __restrict__ w_ih0, const float* __restrict__ w_hh0,
    const float* __restrict__ b_ih0, const float* __restrict__ b_hh0,
    const float* __restrict__ w_ih1, const float* __restrict__ w_hh1,
    const float* __restrict__ b_ih1, const float* __restrict__ b_hh1,
    float* __restrict__ out, unsigned char* __restrict__ ws)
{
  unsigned* F1 = (unsigned*)(ws + WS_F1);
  unsigned* F2 = (unsigned*)(ws + WS_F2);
  unsigned short* Hhi1 = (unsigned short*)(ws + WS_H);
  unsigned short* Hlo1 = Hhi1 + HARR;
  unsigned short* Hhi2 = Hlo1 + HARR;
  unsigned short* Hlo2 = Hhi2 + HARR;

  const int tid  = threadIdx.x;
  const int lane = tid & 63;
  const int wv   = tid >> 6;       // wave 0..3 -> K slice
  const int m16  = lane & 15;      // MFMA row/col lane index
  const int quad = lane >> 4;      // MFMA k-quad
  const int wg    = blockIdx.x;
  const int layer = wg >> 5;
  const int sl    = wg & 31;
  const int j0    = sl * HSL;      // hidden base of this slice
  const int kwb   = wv * KW;

  const float* Wh  = layer ? w_hh1 : w_hh0;
  const float* biL = layer ? b_ih1 : b_ih0;
  const float* bhL = layer ? b_hh1 : b_hh0;

  // ---- recurrent weights -> registers (B-frag layout: n=lane&15, k=quad*8+j)
  bf16x8 Bh_hi[4][4], Bh_lo[4][4];       // [gate][k-chunk]
#pragma unroll
  for (int g = 0; g < 4; ++g)
#pragma unroll
    for (int c = 0; c < 4; ++c){
      int row = g*HH + j0 + m16;
      int k0  = kwb + c*32 + quad*8;
      split8(Wh + (size_t)row*HH + k0, Bh_hi[g][c], Bh_lo[g][c]);
    }
  // ---- input weights
  bf16x8 Bi_hi[4][4], Bi_lo[4][4];
  if (layer){
#pragma unroll
    for (int g = 0; g < 4; ++g)
#pragma unroll
      for (int c = 0; c < 4; ++c){
        int row = g*HH + j0 + m16;
        int k0  = kwb + c*32 + quad*8;
        split8(w_ih1 + (size_t)row*HH + k0, Bi_hi[g][c], Bi_lo[g][c]);
      }
  } else if (wv == 0){               // layer0 input K=32: one chunk, wave0 only
#pragma unroll
    for (int g = 0; g < 4; ++g){
      int row = g*HH + j0 + m16;
      split8(w_ih0 + (size_t)row*32 + quad*8, Bi_hi[g][0], Bi_lo[g][0]);
    }
  }

  // elementwise ownership: thread = (batch eb, hidden-within-slice ej)
  const int eb = tid >> 4;
  const int ej = tid & 15;
  float bias[4];
#pragma unroll
  for (int g = 0; g < 4; ++g){
    int r = g*HH + j0 + ej;
    bias[g] = biL[r] + bhL[r];
  }

  float cst = 0.0f;                      // c[b][j], lives in a register 2048 steps

  __shared__ float P[4][4][16][16];      // [wave][gate][m=b][n=j] partials
  __shared__ int abortf;
  if (tid == 0) abortf = 0;

  const unsigned short* RecHi = layer ? Hhi2 : Hhi1;
  const unsigned short* RecLo = layer ? Hlo2 : Hlo1;
  unsigned short* OutHi = layer ? Hhi2 : Hhi1;
  unsigned short* OutLo = layer ? Hlo2 : Hlo1;
  unsigned* Fown = layer ? F2 : F1;

  for (int t = 0; t < TT; ++t){
    // ---------------- wait for producers ----------------
    if (tid == 0){
      long iters = 0;
      if (layer == 0){
        if (t > 0){
          while (true){
            __builtin_amdgcn_fence(__ATOMIC_ACQUIRE, "agent");
            if (flags_done(F1 + (size_t)t*32)) break;
            if (++iters > 50000000L){ abortf = 1; break; }
          }
        }
      } else {
        while (true){
          __builtin_amdgcn_fence(__ATOMIC_ACQUIRE, "agent");
          bool ok = flags_done(F1 + (size_t)(t+1)*32);   // layer0 output of step t
          if (t > 0) ok = ok && flags_done(F2 + (size_t)t*32);
          if (ok) break;
          if (++iters > 50000000L){ abortf = 1; break; }
        }
      }
      __builtin_amdgcn_fence(__ATOMIC_ACQUIRE, "agent");
    }
    __syncthreads();
    if (abortf) break;     // safety valve: wrong answer instead of a hang

    f32x4 acc[4];
#pragma unroll
    for (int g = 0; g < 4; ++g) acc[g] = f32x4{0.f, 0.f, 0.f, 0.f};

    // ---------------- recurrent matmul: A = own h, slot t ----------------
#pragma unroll
    for (int c = 0; c < 4; ++c){
      int k = kwb + c*32 + quad*8;
      size_t off = ((size_t)t*NB + m16)*HH + k;
      bf16x8 ah = *(const bf16x8*)(RecHi + off);
      bf16x8 al = *(const bf16x8*)(RecLo + off);
#pragma unroll
      for (int g = 0; g < 4; ++g){
        acc[g] = __builtin_amdgcn_mfma_f32_16x16x32_bf16(ah, Bh_hi[g][c], acc[g], 0, 0, 0);
        acc[g] = __builtin_amdgcn_mfma_f32_16x16x32_bf16(al, Bh_hi[g][c], acc[g], 0, 0, 0);
        acc[g] = __builtin_amdgcn_mfma_f32_16x16x32_bf16(ah, Bh_lo[g][c], acc[g], 0, 0, 0);
      }
    }
    // ---------------- input matmul ----------------
    if (layer){                         // A = layer0 output of step t (slot t+1)
#pragma unroll
      for (int c = 0; c < 4; ++c){
        int k = kwb + c*32 + quad*8;
        size_t off = ((size_t)(t+1)*NB + m16)*HH + k;
        bf16x8 ah = *(const bf16x8*)(Hhi1 + off);
        bf16x8 al = *(const bf16x8*)(Hlo1 + off);
#pragma unroll
        for (int g = 0; g < 4; ++g){
          acc[g] = __builtin_amdgcn_mfma_f32_16x16x32_bf16(ah, Bi_hi[g][c], acc[g], 0, 0, 0);
          acc[g] = __builtin_amdgcn_mfma_f32_16x16x32_bf16(al, Bi_hi[g][c], acc[g], 0, 0, 0);
          acc[g] = __builtin_amdgcn_mfma_f32_16x16x32_bf16(ah, Bi_lo[g][c], acc[g], 0, 0, 0);
        }
      }
    } else if (wv == 0){                // layer0: x_t contribution (K=32)
      const float* xp = x + ((size_t)m16*TT + t)*32 + quad*8;
      bf16x8 ah, al;
#pragma unroll
      for (int j = 0; j < 8; ++j){
        float v = xp[j];
        unsigned short h = f2bf(v);
        ah[j] = (short)h;
        al[j] = (short)f2bf(v - bf2f(h));
      }
#pragma unroll
      for (int g = 0; g < 4; ++g){
        acc[g] = __builtin_amdgcn_mfma_f32_16x16x32_bf16(ah, Bi_hi[g][0], acc[g], 0, 0, 0);
        acc[g] = __builtin_amdgcn_mfma_f32_16x16x32_bf16(al, Bi_hi[g][0], acc[g], 0, 0, 0);
        acc[g] = __builtin_amdgcn_mfma_f32_16x16x32_bf16(ah, Bi_lo[g][0], acc[g], 0, 0, 0);
      }
    }

    // ---------------- K-reduction across waves via LDS ----------------
    // D-frag: lane holds D[m=(quad*4+r)][n=lane&15]; m=batch, n=gate row
#pragma unroll
    for (int g = 0; g < 4; ++g)
#pragma unroll
      for (int r = 0; r < 4; ++r)
        P[wv][g][quad*4 + r][m16] = acc[g][r];
    __syncthreads();

    float G[4];
#pragma unroll
    for (int g = 0; g < 4; ++g)
      G[g] = P[0][g][eb][ej] + P[1][g][eb][ej] + P[2][g][eb][ej] + P[3][g][eb][ej] + bias[g];

    // ---------------- LSTM cell (fp32) ----------------
    float gi = sigm(G[0]);
    float gf = sigm(G[1]);
    float gc = tanh_f(G[2]);
    float go = sigm(G[3]);
    cst = gf*cst + gi*gc;
    float h = go * tanh_f(cst);

    // publish h as bf16 hi/lo, packed pairwise into 4B agent-scope stores
    unsigned short hhi = f2bf(h);
    unsigned short hlo = f2bf(h - bf2f(hhi));
    unsigned nhi = (unsigned)__shfl_down((int)hhi, 1, 64) & 0xFFFFu;
    unsigned nlo = (unsigned)__shfl_down((int)hlo, 1, 64) & 0xFFFFu;
    if ((ej & 1) == 0){
      size_t po = ((size_t)(t+1)*NB + eb)*(HH/2) + ((unsigned)(j0 + ej) >> 1);
      __hip_atomic_store((unsigned*)OutHi + po, (unsigned)hhi | (nhi << 16),
                         __ATOMIC_RELAXED, __HIP_MEMORY_SCOPE_AGENT);
      __hip_atomic_store((unsigned*)OutLo + po, (unsigned)hlo | (nlo << 16),
                         __ATOMIC_RELAXED, __HIP_MEMORY_SCOPE_AGENT);
    }

    if (t == TT-1){                     // h_n / c_n outputs
      size_t o = (size_t)layer*NB*HH + (size_t)eb*HH + (j0 + ej);
      out[Y_SZ + o] = h;
      out[Y_SZ + 2*NB*HH + o] = cst;
    }

    __threadfence();                    // order h stores before flag
    __syncthreads();
    if (tid == 0)
      __hip_atomic_store(Fown + (size_t)(t+1)*32 + sl, 1u,
                         __ATOMIC_RELEASE, __HIP_MEMORY_SCOPE_AGENT);
  }
}

// =====================================================================
// y = h2 @ w_out^T + b_out   (parallel epilogue, one block per timestep)
// =====================================================================
__global__ __launch_bounds__(256, 1) void y_proj(
    const unsigned short* __restrict__ Hhi2, const unsigned short* __restrict__ Hlo2,
    const float* __restrict__ w_out, const float* __restrict__ b_out,
    float* __restrict__ out)
{
  __shared__ float hsh[NB][HH + 1];
  __shared__ float wsh[32][HH + 1];
  const int tid = threadIdx.x;
  const int t = blockIdx.x;

  for (int i = tid; i < 32*HH; i += 256){
    int o = i >> 9, k = i & (HH-1);
    wsh[o][k] = w_out[i];
  }
  for (int i = tid; i < NB*HH; i += 256){
    int b = i >> 9, k = i & (HH-1);
    size_t off = ((size_t)(t+1)*NB + b)*HH + k;
    hsh[b][k] = bf2f(Hhi2[off]) + bf2f(Hlo2[off]);
  }
  __syncthreads();

  const int o = tid & 31, bg = tid >> 5;
  float a0 = 0.f, a1 = 0.f;
  for (int k = 0; k < HH; ++k){
    float w = wsh[o][k];
    a0 += w * hsh[bg][k];
    a1 += w * hsh[bg + 8][k];
  }
  float bo = b_out[o];
  out[((size_t)bg*TT + t)*32 + o] = a0 + bo;
  out[((size_t)(bg+8)*TT + t)*32 + o] = a1 + bo;
}

extern "C" void kernel_launch(void* const* d_in, const int* in_sizes, int n_in,
                              void* d_out, int out_size, void* d_ws, size_t ws_size,
                              hipStream_t stream)
{
  (void)in_sizes; (void)n_in; (void)out_size;
  const float* x     = (const float*)d_in[0];
  const float* w_ih0 = (const float*)d_in[1];
  const float* w_hh0 = (const float*)d_in[2];
  const float* b_ih0 = (const float*)d_in[3];
  const float* b_hh0 = (const float*)d_in[4];
  const float* w_ih1 = (const float*)d_in[5];
  const float* w_hh1 = (const float*)d_in[6];
  const float* b_ih1 = (const float*)d_in[7];
  const float* b_hh1 = (const float*)d_in[8];
  const float* w_out = (const float*)d_in[9];
  const float* b_out = (const float*)d_in[10];
  float* out = (float*)d_out;
  unsigned char* ws = (unsigned char*)d_ws;

  const size_t need = (size_t)WS_H + 4*HARR*sizeof(unsigned short);
  if (ws_size < need) return;   // scratch too small -> clean validation failure

  // zero flags + slot-0 h state (ws is re-poisoned before every launch)
  hipMemsetAsync(ws, 0, WS_H, stream);
  for (int a = 0; a < 4; ++a)
    hipMemsetAsync(ws + WS_H + (size_t)a*HARR*2, 0, (size_t)NB*HH*2, stream);

  lstm_persist<<<dim3(2*NSL), dim3(256), 0, stream>>>(
      x, w_ih0, w_hh0, b_ih0, b_hh0, w_ih1, w_hh1, b_ih1, b_hh1, out, ws);

  const unsigned short* Hhi2 = (const unsigned short*)(ws + WS_H) + 2*HARR;
  const unsigned short* Hlo2 = (const unsigned short*)(ws + WS_H) + 3*HARR;
  y_proj<<<dim3(TT), dim3(256), 0, stream>>>(Hhi2, Hlo2, w_out, b_out, out);
}

// Round 2
// 11839.006 us; speedup vs baseline: 1.4241x; 1.4241x over previous
//
#include <hip/hip_runtime.h>

// ---------------- problem constants ----------------
#define TT   2048          // timesteps
#define NB   16            // batch
#define HH   512           // hidden
#define NSL  32            // workgroups per layer (hidden slices)
#define HSL  16            // hidden units per slice
#define KW   128           // K-range per wave (4 waves * 128 = 512)
#define Y_SZ (NB*TT*32)    // y output elements

typedef __attribute__((ext_vector_type(8))) short bf16x8;
typedef __attribute__((ext_vector_type(4))) float f32x4;
typedef unsigned long long ull;

// ---------------- workspace layout (bytes) ----------------
#define WS_F1 0u
#define WS_F2 327680u
#define WS_H  655360u
#define HARR  ((size_t)(TT+1)*NB*HH)   // ushorts per h array

__device__ __forceinline__ unsigned short f2bf(float x){
  unsigned u = __float_as_uint(x);
  return (unsigned short)((u + 0x7FFFu + ((u >> 16) & 1u)) >> 16);
}
__device__ __forceinline__ float bf2f(unsigned short b){
  return __uint_as_float(((unsigned)b) << 16);
}
__device__ __forceinline__ float sigm(float v){ return 1.0f / (1.0f + __expf(-v)); }
__device__ __forceinline__ float tanh_f(float v){
  float a = fabsf(v);
  float e = __expf(-2.0f * a);
  float t = (1.0f - e) / (1.0f + e);
  return v < 0.0f ? -t : t;
}
// split fp32 -> bf16 hi + bf16 lo (hi+lo reproduces fp32 to ~2^-17 rel)
__device__ __forceinline__ void split8(const float* __restrict__ p, bf16x8& hi, bf16x8& lo){
#pragma unroll
  for (int j = 0; j < 8; ++j){
    float w = p[j];
    unsigned short h = f2bf(w);
    hi[j] = (short)h;
    lo[j] = (short)f2bf(w - bf2f(h));
  }
}
// coherent (agent-scope, L1/L2-bypassing) 16B fragment load: two relaxed
// atomic 8B loads -> global_load_dwordx2 ... sc0 sc1, no cache invalidates
__device__ __forceinline__ bf16x8 ld_frag(const unsigned short* p){
  union { ull u[2]; bf16x8 v; } r;
  r.u[0] = __hip_atomic_load((const ull*)p,     __ATOMIC_RELAXED, __HIP_MEMORY_SCOPE_AGENT);
  r.u[1] = __hip_atomic_load((const ull*)p + 1, __ATOMIC_RELAXED, __HIP_MEMORY_SCOPE_AGENT);
  return r.v;
}

// =====================================================================
// Persistent 2-layer LSTM. 64 WGs: wg 0..31 = layer0, 32..63 = layer1.
// Weights pinned in VGPRs as bf16 hi/lo fragments; 3-pass split MFMA.
// Cross-WG handshake: relaxed agent-scope atomics only (no fences ->
// no per-iteration L2 invalidate / per-step L2 writeback).
// =====================================================================
__global__ __launch_bounds__(256, 1) void lstm_persist(
    const float* __restrict__ x,
    const float* __restrict__ w_ih0, const float* __restrict__ w_hh0,
    const float* __restrict__ b_ih0, const float* __restrict__ b_hh0,
    const float* __restrict__ w_ih1, const float* __restrict__ w_hh1,
    const float* __restrict__ b_ih1, const float* __restrict__ b_hh1,
    float* __restrict__ out, unsigned char* __restrict__ ws)
{
  unsigned* F1 = (unsigned*)(ws + WS_F1);
  unsigned* F2 = (unsigned*)(ws + WS_F2);
  unsigned short* Hhi1 = (unsigned short*)(ws + WS_H);
  unsigned short* Hlo1 = Hhi1 + HARR;
  unsigned short* Hhi2 = Hlo1 + HARR;
  unsigned short* Hlo2 = Hhi2 + HARR;

  const int tid  = threadIdx.x;
  const int lane = tid & 63;
  const int wv   = tid >> 6;       // wave 0..3 -> K slice
  const int m16  = lane & 15;      // MFMA row/col lane index
  const int quad = lane >> 4;      // MFMA k-quad
  const int wg    = blockIdx.x;
  const int layer = wg >> 5;
  const int sl    = wg & 31;
  const int j0    = sl * HSL;      // hidden base of this slice
  const int kwb   = wv * KW;

  const float* Wh  = layer ? w_hh1 : w_hh0;
  const float* biL = layer ? b_ih1 : b_ih0;
  const float* bhL = layer ? b_hh1 : b_hh0;

  // ---- recurrent weights -> registers (B-frag layout: n=lane&15, k=quad*8+j)
  bf16x8 Bh_hi[4][4], Bh_lo[4][4];       // [gate][k-chunk]
#pragma unroll
  for (int g = 0; g < 4; ++g)
#pragma unroll
    for (int c = 0; c < 4; ++c){
      int row = g*HH + j0 + m16;
      int k0  = kwb + c*32 + quad*8;
      split8(Wh + (size_t)row*HH + k0, Bh_hi[g][c], Bh_lo[g][c]);
    }
  // ---- input weights
  bf16x8 Bi_hi[4][4], Bi_lo[4][4];
  if (layer){
#pragma unroll
    for (int g = 0; g < 4; ++g)
#pragma unroll
      for (int c = 0; c < 4; ++c){
        int row = g*HH + j0 + m16;
        int k0  = kwb + c*32 + quad*8;
        split8(w_ih1 + (size_t)row*HH + k0, Bi_hi[g][c], Bi_lo[g][c]);
      }
  } else if (wv == 0){               // layer0 input K=32: one chunk, wave0 only
#pragma unroll
    for (int g = 0; g < 4; ++g){
      int row = g*HH + j0 + m16;
      split8(w_ih0 + (size_t)row*32 + quad*8, Bi_hi[g][0], Bi_lo[g][0]);
    }
  }

  // elementwise ownership: thread = (batch eb, hidden-within-slice ej)
  const int eb = tid >> 4;
  const int ej = tid & 15;
  float bias[4];
#pragma unroll
  for (int g = 0; g < 4; ++g){
    int r = g*HH + j0 + ej;
    bias[g] = biL[r] + bhL[r];
  }

  float cst = 0.0f;                      // c[b][j], register-resident all steps

  __shared__ float P[4][4][16][16];      // [wave][gate][m=b][n=j] partials

  const unsigned short* RecHi = layer ? Hhi2 : Hhi1;
  const unsigned short* RecLo = layer ? Hlo2 : Hlo1;
  unsigned short* OutHi = layer ? Hhi2 : Hhi1;
  unsigned short* OutLo = layer ? Hlo2 : Hlo1;
  unsigned* Fown = layer ? F2 : F1;

  for (int t = 0; t < TT; ++t){
    // ---------------- wait for producers (lane-parallel, fence-free) --------
    {
      const unsigned* myflag = nullptr;
      if (layer == 0){
        if (t > 0 && lane < NSL) myflag = F1 + (size_t)t*32 + lane;
      } else {
        if (lane < NSL)                 myflag = F1 + (size_t)(t+1)*32 + lane;
        else if (t > 0 && lane < 2*NSL) myflag = F2 + (size_t)t*32 + (lane - NSL);
      }
      bool done = (myflag == nullptr);
      long iters = 0;
      while (true){
        if (__ballot(!done) == 0ULL) break;
        if (!done){
          unsigned v = __hip_atomic_load(myflag, __ATOMIC_RELAXED, __HIP_MEMORY_SCOPE_AGENT);
          done = (v != 0u);
        }
        if (++iters > 200000000L) break;   // safety valve: garbage, not hang
      }
    }

    f32x4 acc[4];
#pragma unroll
    for (int g = 0; g < 4; ++g) acc[g] = f32x4{0.f, 0.f, 0.f, 0.f};

    // ---------------- recurrent matmul: A = own h, slot t ----------------
#pragma unroll
    for (int c = 0; c < 4; ++c){
      int k = kwb + c*32 + quad*8;
      size_t off = ((size_t)t*NB + m16)*HH + k;
      bf16x8 ah = ld_frag(RecHi + off);
      bf16x8 al = ld_frag(RecLo + off);
#pragma unroll
      for (int g = 0; g < 4; ++g){
        acc[g] = __builtin_amdgcn_mfma_f32_16x16x32_bf16(ah, Bh_hi[g][c], acc[g], 0, 0, 0);
        acc[g] = __builtin_amdgcn_mfma_f32_16x16x32_bf16(al, Bh_hi[g][c], acc[g], 0, 0, 0);
        acc[g] = __builtin_amdgcn_mfma_f32_16x16x32_bf16(ah, Bh_lo[g][c], acc[g], 0, 0, 0);
      }
    }
    // ---------------- input matmul ----------------
    if (layer){                         // A = layer0 output of step t (slot t+1)
#pragma unroll
      for (int c = 0; c < 4; ++c){
        int k = kwb + c*32 + quad*8;
        size_t off = ((size_t)(t+1)*NB + m16)*HH + k;
        bf16x8 ah = ld_frag(Hhi1 + off);
        bf16x8 al = ld_frag(Hlo1 + off);
#pragma unroll
        for (int g = 0; g < 4; ++g){
          acc[g] = __builtin_amdgcn_mfma_f32_16x16x32_bf16(ah, Bi_hi[g][c], acc[g], 0, 0, 0);
          acc[g] = __builtin_amdgcn_mfma_f32_16x16x32_bf16(al, Bi_hi[g][c], acc[g], 0, 0, 0);
          acc[g] = __builtin_amdgcn_mfma_f32_16x16x32_bf16(ah, Bi_lo[g][c], acc[g], 0, 0, 0);
        }
      }
    } else if (wv == 0){                // layer0: x_t contribution (K=32)
      const float* xp = x + ((size_t)m16*TT + t)*32 + quad*8;
      bf16x8 ah, al;
#pragma unroll
      for (int j = 0; j < 8; ++j){
        float v = xp[j];
        unsigned short h = f2bf(v);
        ah[j] = (short)h;
        al[j] = (short)f2bf(v - bf2f(h));
      }
#pragma unroll
      for (int g = 0; g < 4; ++g){
        acc[g] = __builtin_amdgcn_mfma_f32_16x16x32_bf16(ah, Bi_hi[g][0], acc[g], 0, 0, 0);
        acc[g] = __builtin_amdgcn_mfma_f32_16x16x32_bf16(al, Bi_hi[g][0], acc[g], 0, 0, 0);
        acc[g] = __builtin_amdgcn_mfma_f32_16x16x32_bf16(ah, Bi_lo[g][0], acc[g], 0, 0, 0);
      }
    }

    // ---------------- K-reduction across waves via LDS ----------------
    // D-frag: lane holds D[m=(quad*4+r)][n=lane&15]; m=batch, n=gate row
#pragma unroll
    for (int g = 0; g < 4; ++g)
#pragma unroll
      for (int r = 0; r < 4; ++r)
        P[wv][g][quad*4 + r][m16] = acc[g][r];
    __syncthreads();

    float G[4];
#pragma unroll
    for (int g = 0; g < 4; ++g)
      G[g] = P[0][g][eb][ej] + P[1][g][eb][ej] + P[2][g][eb][ej] + P[3][g][eb][ej] + bias[g];

    // ---------------- LSTM cell (fp32) ----------------
    float gi = sigm(G[0]);
    float gf = sigm(G[1]);
    float gc = tanh_f(G[2]);
    float go = sigm(G[3]);
    cst = gf*cst + gi*gc;
    float h = go * tanh_f(cst);

    // publish h as bf16 hi/lo, packed pairwise into 4B agent-scope stores
    unsigned short hhi = f2bf(h);
    unsigned short hlo = f2bf(h - bf2f(hhi));
    unsigned nhi = (unsigned)__shfl_down((int)hhi, 1, 64) & 0xFFFFu;
    unsigned nlo = (unsigned)__shfl_down((int)hlo, 1, 64) & 0xFFFFu;
    if ((ej & 1) == 0){
      size_t po = ((size_t)(t+1)*NB + eb)*(HH/2) + ((unsigned)(j0 + ej) >> 1);
      __hip_atomic_store((unsigned*)OutHi + po, (unsigned)hhi | (nhi << 16),
                         __ATOMIC_RELAXED, __HIP_MEMORY_SCOPE_AGENT);
      __hip_atomic_store((unsigned*)OutLo + po, (unsigned)hlo | (nlo << 16),
                         __ATOMIC_RELAXED, __HIP_MEMORY_SCOPE_AGENT);
    }

    if (t == TT-1){                     // h_n / c_n outputs
      size_t o = (size_t)layer*NB*HH + (size_t)eb*HH + (j0 + ej);
      out[Y_SZ + o] = h;
      out[Y_SZ + 2*NB*HH + o] = cst;
    }

    // drain own stores to the coherence point (no L2 writeback needed:
    // the stores above are agent-scope and already bypass L2)
    asm volatile("s_waitcnt vmcnt(0)" ::: "memory");
    __syncthreads();
    if (tid == 0)
      __hip_atomic_store(Fown + (size_t)(t+1)*32 + sl, 1u,
                         __ATOMIC_RELAXED, __HIP_MEMORY_SCOPE_AGENT);
  }
}

// =====================================================================
// y = h2 @ w_out^T + b_out   (parallel epilogue, one block per timestep)
// =====================================================================
__global__ __launch_bounds__(256, 1) void y_proj(
    const unsigned short* __restrict__ Hhi2, const unsigned short* __restrict__ Hlo2,
    const float* __restrict__ w_out, const float* __restrict__ b_out,
    float* __restrict__ out)
{
  __shared__ float hsh[NB][HH + 1];
  __shared__ float wsh[32][HH + 1];
  const int tid = threadIdx.x;
  const int t = blockIdx.x;

  for (int i = tid; i < 32*HH; i += 256){
    int o = i >> 9, k = i & (HH-1);
    wsh[o][k] = w_out[i];
  }
  for (int i = tid; i < NB*HH; i += 256){
    int b = i >> 9, k = i & (HH-1);
    size_t off = ((size_t)(t+1)*NB + b)*HH + k;
    hsh[b][k] = bf2f(Hhi2[off]) + bf2f(Hlo2[off]);
  }
  __syncthreads();

  const int o = tid & 31, bg = tid >> 5;
  float a0 = 0.f, a1 = 0.f;
  for (int k = 0; k < HH; ++k){
    float w = wsh[o][k];
    a0 += w * hsh[bg][k];
    a1 += w * hsh[bg + 8][k];
  }
  float bo = b_out[o];
  out[((size_t)bg*TT + t)*32 + o] = a0 + bo;
  out[((size_t)(bg+8)*TT + t)*32 + o] = a1 + bo;
}

extern "C" void kernel_launch(void* const* d_in, const int* in_sizes, int n_in,
                              void* d_out, int out_size, void* d_ws, size_t ws_size,
                              hipStream_t stream)
{
  (void)in_sizes; (void)n_in; (void)out_size;
  const float* x     = (const float*)d_in[0];
  const float* w_ih0 = (const float*)d_in[1];
  const float* w_hh0 = (const float*)d_in[2];
  const float* b_ih0 = (const float*)d_in[3];
  const float* b_hh0 = (const float*)d_in[4];
  const float* w_ih1 = (const float*)d_in[5];
  const float* w_hh1 = (const float*)d_in[6];
  const float* b_ih1 = (const float*)d_in[7];
  const float* b_hh1 = (const float*)d_in[8];
  const float* w_out = (const float*)d_in[9];
  const float* b_out = (const float*)d_in[10];
  float* out = (float*)d_out;
  unsigned char* ws = (unsigned char*)d_ws;

  const size_t need = (size_t)WS_H + 4*HARR*sizeof(unsigned short);
  if (ws_size < need) return;   // scratch too small -> clean validation failure

  // zero flags + slot-0 h state (ws is re-poisoned before every launch)
  hipMemsetAsync(ws, 0, WS_H, stream);
  for (int a = 0; a < 4; ++a)
    hipMemsetAsync(ws + WS_H + (size_t)a*HARR*2, 0, (size_t)NB*HH*2, stream);

  lstm_persist<<<dim3(2*NSL), dim3(256), 0, stream>>>(
      x, w_ih0, w_hh0, b_ih0, b_hh0, w_ih1, w_hh1, b_ih1, b_hh1, out, ws);

  const unsigned short* Hhi2 = (const unsigned short*)(ws + WS_H) + 2*HARR;
  const unsigned short* Hlo2 = (const unsigned short*)(ws + WS_H) + 3*HARR;
  y_proj<<<dim3(TT), dim3(256), 0, stream>>>(Hhi2, Hlo2, w_out, b_out, out);
}